// Round 11
// baseline (2621.480 us; speedup 1.0000x reference)
//
#include <hip/hip_runtime.h>

// Problem dims: x[B,T,I], W[H,I], b[H];  B=32, T=2048, I=512, H=1024.
// out = spikes[B,T,H] fp32, then v_f[B,H], then i_f[B,H].
//
// NUMERICS CONTRACT: current[m,n] accumulated as an fp32 fmaf chain over k
// ascending -> bit-identical to reference (absmax 0.0, R3/R4/R6/R8/R9).
// Spikes are a hard threshold; do NOT reassociate (no split-K, no MFMA).
//
// REGISTER RULES (hard-won):
//   - plain __launch_bounds__(256): budget 256 -> 168-184 alloc, no spill.
//   - __launch_bounds__(256,2): budget 128 -> R4 spilled (44GB scratch).
//   - no launch_bounds: 1024-thread default -> 64 VGPRs -> R8 spilled.
// LATENCY RULE (R6/R7/R9): in-loop global->reg operand feeds stall ~200cy
// regardless of 1-group-ahead reg double-buffering (128cy cover < latency).
// Both operands go in LDS; global staging loads are issued right after the
// barrier and consumed at end-of-kt (full-kt cover, R3-proven).
//
// R10 GEMM = R4's 256x128 tile / 16x8 micro-tile (6 ds_read_b128 per 128
// FMAs -> LDS:VALU ratio 1.19, VALU cap ~84% vs R3's 63%) with the correct
// plain __launch_bounds__(256). ~191-reg working set fits the 256 budget.

static constexpr int BM = 256, BN = 128, BK = 16;

__global__ __launch_bounds__(256) void snn_gemm_f32(
    const float* __restrict__ X,    // [M,K]
    const float* __restrict__ Wt,   // [N,K]
    const float* __restrict__ bias, // [N]
    float* __restrict__ C,          // [M,N]
    int M, int N, int K)
{
    __shared__ float As[2][BK][BM + 4]; // [k][m], stride 260 floats
    __shared__ float Bs[2][BK][BN + 4]; // [k][n], stride 132 floats

    const int tid   = threadIdx.x;
    const int mBase = blockIdx.x * BM;  // grid.x = 256 m-panels: 8 n-blocks of
    const int nBase = blockIdx.y * BN;  // a panel share the XCD (256 % 8 == 0)

    const int tx = tid & 15;   // n-group
    const int ty = tid >> 4;   // m-group (0..15)

    // loader mapping: thread loads 4 float4 of X (rows lrow+64p) and 2 of W
    const int lrow = tid >> 2;        // 0..63
    const int lkq  = (tid & 3) << 2;  // 0,4,8,12

    const float* Xp = X + (size_t)(mBase + lrow) * K + lkq;
    const float* Wp = Wt + (size_t)(nBase + lrow) * K + lkq;
    const size_t rowStride64 = (size_t)64 * K;

    float acc[16][8];
#pragma unroll
    for (int i = 0; i < 16; ++i)
#pragma unroll
        for (int j = 0; j < 8; ++j) acc[i][j] = 0.f;

    float4 ra[4], rb[2];

    // prologue: k-tile 0 -> buffer 0
#pragma unroll
    for (int p = 0; p < 4; ++p) ra[p] = *(const float4*)(Xp + p * rowStride64);
#pragma unroll
    for (int p = 0; p < 2; ++p) rb[p] = *(const float4*)(Wp + p * rowStride64);

    {
        float* a0 = &As[0][0][0];
        float* b0 = &Bs[0][0][0];
#pragma unroll
        for (int p = 0; p < 4; ++p) {
            a0[(lkq + 0) * (BM + 4) + lrow + 64 * p] = ra[p].x;
            a0[(lkq + 1) * (BM + 4) + lrow + 64 * p] = ra[p].y;
            a0[(lkq + 2) * (BM + 4) + lrow + 64 * p] = ra[p].z;
            a0[(lkq + 3) * (BM + 4) + lrow + 64 * p] = ra[p].w;
        }
#pragma unroll
        for (int p = 0; p < 2; ++p) {
            b0[(lkq + 0) * (BN + 4) + lrow + 64 * p] = rb[p].x;
            b0[(lkq + 1) * (BN + 4) + lrow + 64 * p] = rb[p].y;
            b0[(lkq + 2) * (BN + 4) + lrow + 64 * p] = rb[p].z;
            b0[(lkq + 3) * (BN + 4) + lrow + 64 * p] = rb[p].w;
        }
    }
    __syncthreads();

    const int nk = K / BK; // 32
#pragma unroll 1
    for (int kt = 0; kt < nk; ++kt) {
        const int cur = kt & 1;
        const bool more = (kt + 1) < nk;
        if (more) {
            const int k0 = (kt + 1) * BK;
#pragma unroll
            for (int p = 0; p < 4; ++p) ra[p] = *(const float4*)(Xp + k0 + p * rowStride64);
#pragma unroll
            for (int p = 0; p < 2; ++p) rb[p] = *(const float4*)(Wp + k0 + p * rowStride64);
        }

        const float (*as)[BM + 4] = As[cur];
        const float (*bs)[BN + 4] = Bs[cur];
#pragma unroll
        for (int kk = 0; kk < BK; ++kk) {
            float a[16], b[8];
            *(float4*)&a[0]  = *(const float4*)&as[kk][ty * 4];
            *(float4*)&a[4]  = *(const float4*)&as[kk][ty * 4 + 64];
            *(float4*)&a[8]  = *(const float4*)&as[kk][ty * 4 + 128];
            *(float4*)&a[12] = *(const float4*)&as[kk][ty * 4 + 192];
            *(float4*)&b[0]  = *(const float4*)&bs[kk][tx * 4];
            *(float4*)&b[4]  = *(const float4*)&bs[kk][tx * 4 + 64];
#pragma unroll
            for (int i = 0; i < 16; ++i)
#pragma unroll
                for (int j = 0; j < 8; ++j)
                    acc[i][j] = fmaf(a[i], b[j], acc[i][j]);
        }

        if (more) {
            const int nxt = cur ^ 1;
            float* a0 = &As[nxt][0][0];
            float* b0 = &Bs[nxt][0][0];
#pragma unroll
            for (int p = 0; p < 4; ++p) {
                a0[(lkq + 0) * (BM + 4) + lrow + 64 * p] = ra[p].x;
                a0[(lkq + 1) * (BM + 4) + lrow + 64 * p] = ra[p].y;
                a0[(lkq + 2) * (BM + 4) + lrow + 64 * p] = ra[p].z;
                a0[(lkq + 3) * (BM + 4) + lrow + 64 * p] = ra[p].w;
            }
#pragma unroll
            for (int p = 0; p < 2; ++p) {
                b0[(lkq + 0) * (BN + 4) + lrow + 64 * p] = rb[p].x;
                b0[(lkq + 1) * (BN + 4) + lrow + 64 * p] = rb[p].y;
                b0[(lkq + 2) * (BN + 4) + lrow + 64 * p] = rb[p].z;
                b0[(lkq + 3) * (BN + 4) + lrow + 64 * p] = rb[p].w;
            }
        }
        __syncthreads();
    }

    // epilogue: bias + coalesced stores (verified bit-exact in R4)
    const float4 bb0 = *(const float4*)(bias + nBase + tx * 4);
    const float4 bb1 = *(const float4*)(bias + nBase + 64 + tx * 4);
#pragma unroll
    for (int c = 0; c < 4; ++c)
#pragma unroll
        for (int r = 0; r < 4; ++r) {
            const int i = c * 4 + r;
            const size_t row = (size_t)(mBase + c * 64 + ty * 4 + r);
            float4 o0, o1;
            o0.x = acc[i][0] + bb0.x; o0.y = acc[i][1] + bb0.y;
            o0.z = acc[i][2] + bb0.z; o0.w = acc[i][3] + bb0.w;
            o1.x = acc[i][4] + bb1.x; o1.y = acc[i][5] + bb1.y;
            o1.z = acc[i][6] + bb1.z; o1.w = acc[i][7] + bb1.w;
            *(float4*)(C + row * N + nBase + tx * 4)      = o0;
            *(float4*)(C + row * N + nBase + 64 + tx * 4) = o1;
        }
}

// ---------------------------------------------------------------------------
// LIF scan: one thread per neuron (b,h); U=32 prefetch double-buffer.
// In-place safe when cur aliases spk (read t precedes write t per thread).
// ---------------------------------------------------------------------------
__global__ __launch_bounds__(64) void snn_scan(
    const float* cur, float* spk, float* vf, float* iff,
    int T, int H)
{
    const int idx = blockIdx.x * blockDim.x + threadIdx.x; // 0..B*H-1
    const int h = idx & (H - 1);
    const int b = idx >> 10; // H = 1024
    const size_t base = ((size_t)b * T) * H + h;

    constexpr int U = 32;
    float ca[U];
#pragma unroll
    for (int j = 0; j < U; ++j) ca[j] = cur[base + (size_t)j * H];

    float v = 0.f, ii = 0.f;
    for (int t0 = 0; t0 < T; t0 += U) {
        float cb[U];
        const bool pref = (t0 + U) < T;
#pragma unroll
        for (int j = 0; j < U; ++j)
            cb[j] = pref ? cur[base + (size_t)(t0 + U + j) * H] : 0.f;
#pragma unroll
        for (int j = 0; j < U; ++j) {
            const float v_dec = v + 0.1f * ((0.0f - v) + ii);
            const float i_dec = ii - 0.2f * ii;
            const float z = (v_dec > 1.0f) ? 1.0f : 0.0f;
            v  = (v_dec > 1.0f) ? 0.0f : v_dec;
            ii = i_dec + ca[j];
            spk[base + (size_t)(t0 + j) * H] = z;
        }
#pragma unroll
        for (int j = 0; j < U; ++j) ca[j] = cb[j];
    }
    vf[idx]  = v;
    iff[idx] = ii;
}

// ---------------------------------------------------------------------------
extern "C" void kernel_launch(void* const* d_in, const int* in_sizes, int n_in,
                              void* d_out, int out_size, void* d_ws, size_t ws_size,
                              hipStream_t stream) {
    const int B = 32, T = 2048, I = 512, H = 1024;
    const int M = B * T, N = H, K = I;

    const float* x    = (const float*)d_in[0];
    const float* W    = (const float*)d_in[1];
    const float* bias = (const float*)d_in[2];

    float* out    = (float*)d_out;
    float* spikes = out;                        // [B,T,H]
    float* vf     = out + (size_t)B * T * H;    // [B,H]
    float* iff    = vf + (size_t)B * H;         // [B,H]

    const size_t curBytes = (size_t)B * T * H * sizeof(float);
    float* curbuf = (ws_size >= curBytes) ? (float*)d_ws : spikes;

    dim3 grid(M / BM, N / BN); // (256, 8): x = m-panel (XCD-local n-blocks)
    snn_gemm_f32<<<grid, 256, 0, stream>>>(x, W, bias, curbuf, M, N, K);

    const int nNeuron = B * H; // 32768
    snn_scan<<<nNeuron / 64, 64, 0, stream>>>(curbuf, spikes, vf, iff, T, H);
}